// Round 7
// baseline (44.679 us; speedup 1.0000x reference)
//
#include <hip/hip_runtime.h>

// Problem constants (reference: B=8, T=2000, N=2048, penalty=10.0)
#define B_CONST 8
#define T_CONST 2000
#define N_CONST 2048
#define WPB 4                   // waves per block (block = 256 threads)
#define TSEG (T_CONST / WPB)    // 500 timesteps per wave
#define UNR 20                  // prefetch batch; 500 % 20 == 0
#define PENALTY 10.0f

// One block per (b, 64-neuron slice): 8 * 32 = 256 blocks = exactly 1 per CU.
// Each wave scans a T-quarter for its 64 neurons (1 n per lane, coalesced
// 256B per load instr); partials merge in LDS; no global partials at all.
// Stats (cnt, t_first, t_last, sum ISI^2) are exact integers (< 2^22), so the
// chunked merge is bit-identical to the reference's per-(b,n) statistics.

__global__ __launch_bounds__(256) void cv_all_kernel(const float* __restrict__ x,
                                                     const float* __restrict__ tcv,
                                                     float* __restrict__ out) {
    const int l  = threadIdx.x & 63;          // lane -> neuron
    const int w  = threadIdx.x >> 6;          // wave -> time quarter
    const int b  = blockIdx.x >> 5;           // 32 blocks per batch row
    const int n  = ((blockIdx.x & 31) << 6) + l;
    const int t0 = w * TSEG;

    const float* p = x + ((size_t)b * T_CONST + t0) * (size_t)N_CONST + n;

    int cnt = 0, frst = 0, last = 0, s2 = 0;
    bool has = false;

    for (int base = 0; base < TSEG; base += UNR) {
        float buf[UNR];
#pragma unroll
        for (int u = 0; u < UNR; ++u)                      // issue 20 loads in flight
            buf[u] = p[(size_t)(base + u) * N_CONST];
#pragma unroll
        for (int u = 0; u < UNR; ++u) {                    // branchless scan
            const int  t    = t0 + base + u;
            const bool sp   = buf[u] > 0.0f;
            const int  d    = t - last;
            const int  dsel = (sp && has) ? d : 0;
            s2  += __mul24(dsel, dsel);                    // exact, < 2^22
            frst = (sp && !has) ? t : frst;
            last = sp ? t : last;
            cnt += sp ? 1 : 0;
            has  = has || sp;
        }
    }

    // merge the 4 time-quarters (ascending time order) in LDS
    __shared__ int4 lds[WPB][64];
    lds[w][l] = make_int4(cnt, frst, last, s2);
    __syncthreads();

    if (w == 0) {
        int mc = 0, mf = 0, ml = 0, ms = 0;
#pragma unroll
        for (int q = 0; q < WPB; ++q) {
            const int4 pp = lds[q][l];
            const bool hp = pp.x > 0;
            const bool hm = mc > 0;
            const int  d  = pp.y - ml;                     // cross-quarter ISI
            const int  m2 = ms + pp.w + __mul24(d, d);
            ms  = hp ? (hm ? m2 : pp.w) : ms;
            mf  = (hp && !hm) ? pp.y : mf;
            ml  = hp ? pp.z : ml;
            mc += hp ? pp.x : 0;
        }

        float cvs;
        if (mc >= 3) {                 // count>=3 implies mean_isi>0 (integer times)
            const float k    = (float)(mc - 1);
            const float mean = (float)(ml - mf) / k;       // telescoped sum of ISIs
            const float var  = fmaxf(((float)ms - k * mean * mean) / (k - 1.0f), 0.0f);
            cvs = sqrtf(var) / mean;
        } else {
            cvs = PENALTY;
        }
        const float dd = cvs - tcv[n];
        float e = dd * dd;

        // wave64 shuffle reduce -> one atomic per block (256 total)
#pragma unroll
        for (int o = 32; o > 0; o >>= 1) e += __shfl_down(e, o, 64);
        if (l == 0)
            atomicAdd(out, e * (1.0f / ((float)B_CONST * (float)N_CONST)));
    }
}

extern "C" void kernel_launch(void* const* d_in, const int* in_sizes, int n_in,
                              void* d_out, int out_size, void* d_ws, size_t ws_size,
                              hipStream_t stream) {
    const float* x   = (const float*)d_in[0];   // (B,T,N) fp32
    const float* tcv = (const float*)d_in[1];   // (N,) fp32
    float* out = (float*)d_out;

    hipMemsetAsync(d_out, 0, sizeof(float), stream);   // replay-safe zero init

    cv_all_kernel<<<dim3(B_CONST * (N_CONST / 64)), dim3(256), 0, stream>>>(x, tcv, out);
}

// Round 8
// 33.443 us; speedup vs baseline: 1.3360x; 1.3360x over previous
//
#include <hip/hip_runtime.h>

// Problem constants (reference: B=8, T=2000, N=2048, penalty=10.0)
#define B_CONST 8
#define T_CONST 2000
#define N_CONST 2048
#define ZC 32                 // time chunks; grid (4,8,32)=1024 blocks = 4/CU exactly
#define CPW 4                 // chunks merged per wave in kernel 2 (8 waves)
#define PENALTY 10.0f

// Partial per (b, n, chunk) packed in float2 (8 B):
//   .x bits = (cnt << 22) | (t_first << 11) | t_last   (cnt<=63, times<2048)
//   .y      = sum ISI^2  (integer < 2^22, exact in fp32)
// Monoid combine (time-ordered): if both nonempty, s2 += (R.first - L.last)^2.
// All quantities are exact integers -> matches reference per (b,n) bit-for-bit.

__global__ __launch_bounds__(128) void cv_partial_kernel(const float* __restrict__ x,
                                                         float2* __restrict__ ws,
                                                         float* __restrict__ out) {
    // fold d_out zero-init here (saves a dispatch); kernel 2 is stream-ordered after us
    if (threadIdx.x == 0 && blockIdx.x == 0 && blockIdx.y == 0 && blockIdx.z == 0)
        *out = 0.0f;

    const int n0 = blockIdx.x * 512 + threadIdx.x * 4;  // 4 consecutive n per thread
    const int b  = blockIdx.y;
    const int z  = blockIdx.z;
    const int t0   = (z * 125) >> 1;                    // ragged 62/63-step chunks
    const int tend = ((z + 1) * 125) >> 1;

    const float* p = x + ((size_t)b * T_CONST + t0) * (size_t)N_CONST + n0;

    int  cnt[4]  = {0, 0, 0, 0};
    int  frst[4] = {0, 0, 0, 0};
    int  last[4] = {0, 0, 0, 0};
    int  s2[4]   = {0, 0, 0, 0};
    bool has[4]  = {false, false, false, false};

#pragma unroll 8
    for (int t = t0; t < tend; ++t) {
        const float4 v = *reinterpret_cast<const float4*>(p);
        p += N_CONST;
        const float vv[4] = {v.x, v.y, v.z, v.w};
#pragma unroll
        for (int j = 0; j < 4; ++j) {                   // branchless: selects only
            const bool sp   = vv[j] > 0.0f;
            const int  d    = t - last[j];
            const int  dsel = (sp && has[j]) ? d : 0;
            s2[j]  += __mul24(dsel, dsel);              // exact, < 2^22
            frst[j] = (sp && !has[j]) ? t : frst[j];
            last[j] = sp ? t : last[j];
            cnt[j] += sp ? 1 : 0;
            has[j]  = has[j] || sp;
        }
    }

    // pack + store: 4 partials = 32 B = two dwordx4, 32B-aligned
    float4* w = reinterpret_cast<float4*>(ws + ((size_t)(b * ZC + z) * N_CONST) + n0);
    float meta[4], s2f[4];
#pragma unroll
    for (int j = 0; j < 4; ++j) {
        const unsigned m = ((unsigned)cnt[j] << 22) |
                           ((unsigned)frst[j] << 11) |
                            (unsigned)last[j];
        meta[j] = __uint_as_float(m);
        s2f[j]  = (float)s2[j];
    }
    w[0] = make_float4(meta[0], s2f[0], meta[1], s2f[1]);
    w[1] = make_float4(meta[2], s2f[2], meta[3], s2f[3]);
}

__global__ __launch_bounds__(512) void cv_final_kernel(const float2* __restrict__ ws,
                                                       const float* __restrict__ tcv,
                                                       float* __restrict__ out) {
    const int l   = threadIdx.x & 63;               // lane -> (b,n) item
    const int w   = threadIdx.x >> 6;               // wave (0..7) -> chunk segment
    const int gid = blockIdx.x * 64 + l;            // 0 .. B*N-1 (64 divides N)
    const int b   = gid >> 11;
    const int n   = gid & (N_CONST - 1);

    // each wave merges its 4 chunks, branchless so loads pipeline
    float mc = 0.f, mf = 0.f, ml = 0.f, ms = 0.f;
    const float2* base = ws + ((size_t)(b * ZC + w * CPW) * N_CONST) + n;
#pragma unroll
    for (int i = 0; i < CPW; ++i) {
        const float2 pp = base[(size_t)i * N_CONST];    // coalesced 512B per wave
        const unsigned meta = __float_as_uint(pp.x);
        const float pc = (float)(meta >> 22);
        const float pf = (float)((meta >> 11) & 2047u);
        const float pl = (float)(meta & 2047u);
        const bool hp = pc > 0.0f;
        const bool hm = mc > 0.0f;
        const float d  = pf - ml;
        const float m2 = ms + pp.y + d * d;
        ms  = hp ? (hm ? m2 : pp.y) : ms;
        mf  = (hp && !hm) ? pf : mf;
        ml  = hp ? pl : ml;
        mc += hp ? pc : 0.0f;
    }

    __shared__ float4 lds[8][64];
    lds[w][l] = make_float4(mc, mf, ml, ms);
    __syncthreads();

    if (w == 0) {
        mc = 0.f; mf = 0.f; ml = 0.f; ms = 0.f;
#pragma unroll
        for (int q = 0; q < 8; ++q) {               // time-ordered 8-way combine
            const float4 pp = lds[q][l];
            const bool hp = pp.x > 0.0f;
            const bool hm = mc > 0.0f;
            const float d  = pp.y - ml;
            const float m2 = ms + pp.w + d * d;
            ms  = hp ? (hm ? m2 : pp.w) : ms;
            mf  = (hp && !hm) ? pp.y : mf;
            ml  = hp ? pp.z : ml;
            mc += hp ? pp.x : 0.0f;
        }

        float cvs;
        if (mc >= 3.0f) {                 // count>=3 implies mean_isi>0 (integer times)
            const float k    = mc - 1.0f;
            const float mean = (ml - mf) / k;          // telescoped sum of ISIs
            const float var  = fmaxf((ms - k * mean * mean) / (k - 1.0f), 0.0f);
            cvs = sqrtf(var) / mean;
        } else {
            cvs = PENALTY;
        }
        const float dd = cvs - tcv[n];
        float e = dd * dd;

#pragma unroll
        for (int o = 32; o > 0; o >>= 1) e += __shfl_down(e, o, 64);
        if (l == 0)
            atomicAdd(out, e * (1.0f / ((float)B_CONST * (float)N_CONST)));
    }
}

extern "C" void kernel_launch(void* const* d_in, const int* in_sizes, int n_in,
                              void* d_out, int out_size, void* d_ws, size_t ws_size,
                              hipStream_t stream) {
    const float* x   = (const float*)d_in[0];   // (B,T,N) fp32
    const float* tcv = (const float*)d_in[1];   // (N,) fp32
    float* out  = (float*)d_out;
    float2* ws  = (float2*)d_ws;                // needs B*ZC*N*8 = 4.19 MB

    dim3 g1(N_CONST / 512, B_CONST, ZC);        // (4, 8, 32) = 1024 blocks = 4/CU
    cv_partial_kernel<<<g1, dim3(128), 0, stream>>>(x, ws, out);

    cv_final_kernel<<<(B_CONST * N_CONST) / 64, dim3(512), 0, stream>>>(ws, tcv, out);
}